// Round 9
// baseline (606.923 us; speedup 1.0000x reference)
//
#include <hip/hip_runtime.h>
#include <hip/hip_cooperative_groups.h>

namespace cg = cooperative_groups;

// RGATConv x2 (N=50000, E=800000, IN=HID=128, R=8) for MI355X/gfx950.
//
// Round-17: sort chain fused into ONE cooperative kernel (k_sort): edges
// loaded once into registers, bucket-count -> scan -> stage -> per-bucket
// scatter with grid.sync() between phases. Replaces 4 dispatches (count,
// bucket_scan, bin, scatter2) and the 26MB of edge re-reads. Falls back to
// the verified 4-kernel path if cooperative launch is rejected.
// gemm/aggregate/preps identical to round-16 (merged dispatches, cvt_pk).

typedef unsigned short u16;
typedef __attribute__((ext_vector_type(8))) short short8;
typedef __attribute__((ext_vector_type(4))) float floatx4;
typedef __attribute__((ext_vector_type(4))) float float4v;
typedef __attribute__((ext_vector_type(4))) unsigned uint4v;

__device__ __forceinline__ u16 f2bf(float f) {
  union { float f; unsigned u; } v; v.f = f;
  unsigned r = v.u + 0x7FFFu + ((v.u >> 16) & 1u);  // RNE
  return (u16)(r >> 16);
}
__device__ __forceinline__ float bflo(unsigned v) {
  union { unsigned u; float f; } c; c.u = v << 16; return c.f;
}
__device__ __forceinline__ float bfhi(unsigned v) {
  union { unsigned u; float f; } c; c.u = v & 0xffff0000u; return c.f;
}
__device__ __forceinline__ unsigned cvtpk(float lo, float hi) {
  unsigned r;
  asm("v_cvt_pk_bf16_f32 %0, %1, %2" : "=v"(r) : "v"(lo), "v"(hi));
  return r;
}

// ---- 1. pack stacked W into fragment order (per graph) ----------------------
__global__ void k_prep_wb(const float* __restrict__ W1, const float* __restrict__ W2,
                          u16* __restrict__ Wb, int KK) {
  int t = blockIdx.x * 256 + threadIdx.x;
  int lane = t & 63, nt = (t >> 6) & 7, kk = t >> 9;
  if (kk >= KK) return;
  const float* W = blockIdx.y ? W2 : W1;
  u16* out = Wb + (size_t)blockIdx.y * KK * 4096;
  int q = lane >> 4, m16 = lane & 15;
  int c = nt * 16 + m16;
  short8 v;
#pragma unroll
  for (int j = 0; j < 8; ++j) {
    int k = kk * 32 + q * 8 + j;
    v[j] = (short)f2bf(W[(size_t)k * 128 + c]);
  }
  *(short8*)(out + (size_t)t * 8) = v;
}

// ---- 2. Bqk direct: Bqk[g][kk][lane][j] = dot(W_g[r][k][:], {q|k}_g) --------
__global__ void __launch_bounds__(256) k_prep_bqk(
    const float* __restrict__ W1, const float* __restrict__ q1,
    const float* __restrict__ k1, const float* __restrict__ W2,
    const float* __restrict__ q2, const float* __restrict__ k2,
    u16* __restrict__ Bqk) {
  int idx = blockIdx.x * 256 + threadIdx.x;  // 4096 total
  int j = idx & 7, lane = (idx >> 3) & 63, kk = (idx >> 9) & 3, g = idx >> 11;
  int k = kk * 32 + ((lane >> 4) & 3) * 8 + j;
  int n = lane & 15;
  const float* W = g ? W2 : W1;
  const float* vec = (n < 8) ? (g ? q2 : q1) : (g ? k2 : k1);
  const float* row = W + ((size_t)(n & 7) * 128 + k) * 128;
  float s = 0.f;
#pragma unroll
  for (int o = 0; o < 128; o += 4) {
    float4v wv = *(const float4v*)(row + o);
    float4v qv = *(const float4v*)(vec + o);
    s += wv.x * qv.x + wv.y * qv.y + wv.z * qv.z + wv.w * qv.w;
  }
  Bqk[idx] = f2bf(s);
}

// ---- 5. FUSED cooperative sort ----------------------------------------------
// Grid = max(nbin, NB) blocks x 256. Phases:
//  1: load 4096 edges -> regs; LDS bucket hist; += gcnt (global)
//  2: block 0 scans gcnt -> bbase/bcur; offs[N2] = total
//  3: runstart = atomicAdd(bcur); stage regs -> LDS sta -> staged (global)
//  4: block b = bucket b: node-level hist/scan -> offs, scatter -> csr
__global__ void __launch_bounds__(256) k_sort(
    const int* __restrict__ ei1, const int* __restrict__ et1,
    const int* __restrict__ ei2, const int* __restrict__ et2,
    int* __restrict__ gcnt, int* __restrict__ bbase, int* __restrict__ bcur,
    int* __restrict__ offs, uint2* __restrict__ staged, int* __restrict__ csr,
    int N, int E, int NB, int N2, int total) {
  __shared__ int hist[512];
  __shared__ int basev[512];
  __shared__ int runstart[512];
  __shared__ unsigned sta[4096 * 2];  // 32 KB
  cg::grid_group grid = cg::this_grid();
  int tid = threadIdx.x;
  int E2 = 2 * E;
  int e0 = blockIdx.x * 4096;
  bool has_edges = (e0 < E2);
  int cnt2 = has_edges ? min(4096, E2 - e0) : 0;

  // ---- phase 1: count ----
  for (int i = tid; i < 512; i += 256) hist[i] = 0;
  __syncthreads();
  int dstg[16], srcet[16], rank[16];
#pragma unroll
  for (int j = 0; j < 16; ++j) dstg[j] = -1;
  if (has_edges) {
#pragma unroll
    for (int j = 0; j < 16; ++j) {
      int e = e0 + j * 256 + tid;
      if (e < E2) {
        int g = e >= E;
        int el = e - (g ? E : 0);
        const int* ei = g ? ei2 : ei1;
        int s = ei[el], d = ei[E + el];
        int etv = (g ? et2 : et1)[el];
        dstg[j] = g * N + d;
        srcet[j] = (s << 3) | etv;
        rank[j] = atomicAdd(&hist[dstg[j] >> 8], 1);
      }
    }
    __syncthreads();
    for (int i = tid; i < NB; i += 256)
      if (hist[i]) atomicAdd(&gcnt[i], hist[i]);
  }
  __threadfence();
  grid.sync();

  // ---- phase 2: bucket scan (block 0; basev as scratch, hist preserved) ----
  if (blockIdx.x == 0) {
    int v0 = (tid < NB) ? gcnt[tid] : 0;
    int v1 = (tid + 256 < NB) ? gcnt[tid + 256] : 0;
    basev[tid] = v0; basev[tid + 256] = v1;
    __syncthreads();
    for (int off = 1; off < 512; off <<= 1) {
      int t0 = (tid >= off) ? basev[tid - off] : 0;
      int t1 = (tid + 256 >= off) ? basev[tid + 256 - off] : 0;
      __syncthreads();
      basev[tid] += t0; basev[tid + 256] += t1;
      __syncthreads();
    }
    if (tid < NB) { int b = basev[tid] - v0; bbase[tid] = b; bcur[tid] = b; }
    if (tid + 256 < NB) { int b = basev[tid + 256] - v1; bbase[tid + 256] = b; bcur[tid + 256] = b; }
    if (tid == 0) { bbase[NB] = total; offs[N2] = total; }
  }
  __threadfence();
  grid.sync();

  // ---- phase 3: stage into bucket-grouped order ----
  if (has_edges) {
    basev[tid] = hist[tid];
    basev[tid + 256] = hist[tid + 256];
    __syncthreads();
    for (int off = 1; off < 512; off <<= 1) {
      int v0 = (tid >= off) ? basev[tid - off] : 0;
      int v1 = (tid + 256 >= off) ? basev[tid + 256 - off] : 0;
      __syncthreads();
      basev[tid] += v0; basev[tid + 256] += v1;
      __syncthreads();
    }
    for (int i = tid; i < NB; i += 256)
      if (hist[i] > 0) runstart[i] = atomicAdd(&bcur[i], hist[i]);
    __syncthreads();
#pragma unroll
    for (int j = 0; j < 16; ++j)
      if (dstg[j] >= 0) {
        int b = dstg[j] >> 8;
        int slot = basev[b] - hist[b] + rank[j];
        sta[slot * 2] = (unsigned)dstg[j];
        sta[slot * 2 + 1] = (unsigned)srcet[j];
      }
    __syncthreads();
    for (int i = tid; i < cnt2; i += 256) {
      unsigned dg = sta[i * 2], se = sta[i * 2 + 1];
      int b = (int)(dg >> 8);
      int dest = runstart[b] + (i - (basev[b] - hist[b]));
      staged[dest] = make_uint2(dg, se);
    }
  }
  __threadfence();
  grid.sync();

  // ---- phase 4: per-bucket node-level offs + csr (LDS reused) ----
  if ((int)blockIdx.x < NB) {
    int nb0 = blockIdx.x << 8;
    int nnode = min(256, N2 - nb0);
    int s0 = bbase[blockIdx.x], s1 = bbase[blockIdx.x + 1];
    hist[tid] = 0;
    __syncthreads();
    for (int i = s0 + tid; i < s1; i += 256)
      atomicAdd(&hist[(int)staged[i].x - nb0], 1);
    __syncthreads();
    int v = hist[tid];
    basev[tid] = v;
    __syncthreads();
    for (int off = 1; off < 256; off <<= 1) {
      int t = (tid >= off) ? basev[tid - off] : 0;
      __syncthreads();
      basev[tid] += t;
      __syncthreads();
    }
    int ex = basev[tid] - v;  // exclusive scan
    if (tid < nnode) offs[nb0 + tid] = s0 + ex;
    runstart[tid] = ex;  // cur
    __syncthreads();
    for (int i = s0 + tid; i < s1; i += 256) {
      uint2 en = staged[i];
      int node = (int)en.x - nb0;
      int sl = atomicAdd(&runstart[node], 1);
      csr[s0 + sl] = (int)en.y;
    }
  }
}

// ---- 5-fallback kernels (verified round-11/16 path) -------------------------
__global__ void __launch_bounds__(256) k_count(
    const int* __restrict__ d1, const int* __restrict__ d2,
    int* __restrict__ gcnt, int N, int E, int NB) {
  __shared__ int h[512];
  int tid = threadIdx.x;
  for (int i = tid; i < NB; i += 256) h[i] = 0;
  __syncthreads();
  int E2 = 2 * E;
  int e0 = blockIdx.x * 4096;
#pragma unroll
  for (int j = 0; j < 16; ++j) {
    int e = e0 + j * 256 + tid;
    if (e < E2) {
      int g = e >= E;
      int d = g ? d2[e - E] : d1[e];
      atomicAdd(&h[(g * N + d) >> 8], 1);
    }
  }
  __syncthreads();
  for (int i = tid; i < NB; i += 256)
    if (h[i]) atomicAdd(&gcnt[i], h[i]);
}

__global__ void k_bucket_scan(const int* __restrict__ gcnt, int* __restrict__ bbase,
                              int* __restrict__ bcur, int* __restrict__ offs,
                              int NB, int total, int N2) {
  __shared__ int sd[512];
  int tid = threadIdx.x;
  int v0 = (tid < NB) ? gcnt[tid] : 0;
  int v1 = (tid + 256 < NB) ? gcnt[tid + 256] : 0;
  sd[tid] = v0; sd[tid + 256] = v1;
  __syncthreads();
  for (int off = 1; off < 512; off <<= 1) {
    int t0 = (tid >= off) ? sd[tid - off] : 0;
    int t1 = (tid + 256 >= off) ? sd[tid + 256 - off] : 0;
    __syncthreads();
    sd[tid] += t0; sd[tid + 256] += t1;
    __syncthreads();
  }
  if (tid < NB) { int b = sd[tid] - v0; bbase[tid] = b; bcur[tid] = b; }
  if (tid + 256 < NB) { int b = sd[tid + 256] - v1; bbase[tid + 256] = b; bcur[tid + 256] = b; }
  if (tid == 0) { bbase[NB] = total; offs[N2] = total; }
}

__global__ void __launch_bounds__(256) k_bin(
    const int* __restrict__ ei1, const int* __restrict__ et1,
    const int* __restrict__ ei2, const int* __restrict__ et2,
    int* __restrict__ bcur, uint2* __restrict__ staged, int N, int E, int NB) {
  __shared__ int hist[512];
  __shared__ int basev[512];
  __shared__ int runstart[512];
  __shared__ unsigned sta[4096 * 2];
  int tid = threadIdx.x;
  int E2 = 2 * E;
  int e0 = blockIdx.x * 4096;
  int cnt2 = min(4096, E2 - e0);
  for (int i = tid; i < 512; i += 256) hist[i] = 0;
  __syncthreads();
  int dstg[16], srcet[16], rank[16];
#pragma unroll
  for (int j = 0; j < 16; ++j) {
    int e = e0 + j * 256 + tid;
    dstg[j] = -1;
    if (e < E2) {
      int g = e >= E;
      int el = e - (g ? E : 0);
      const int* ei = g ? ei2 : ei1;
      int s = ei[el], d = ei[E + el];
      int etv = (g ? et2 : et1)[el];
      dstg[j] = g * N + d;
      srcet[j] = (s << 3) | etv;
      rank[j] = atomicAdd(&hist[dstg[j] >> 8], 1);
    }
  }
  __syncthreads();
  basev[tid] = hist[tid];
  basev[tid + 256] = hist[tid + 256];
  __syncthreads();
  for (int off = 1; off < 512; off <<= 1) {
    int i0 = tid, i1 = tid + 256;
    int v0 = (i0 >= off) ? basev[i0 - off] : 0;
    int v1 = (i1 >= off) ? basev[i1 - off] : 0;
    __syncthreads();
    basev[i0] += v0; basev[i1] += v1;
    __syncthreads();
  }
  for (int i = tid; i < NB; i += 256)
    if (hist[i] > 0) runstart[i] = atomicAdd(&bcur[i], hist[i]);
  __syncthreads();
#pragma unroll
  for (int j = 0; j < 16; ++j)
    if (dstg[j] >= 0) {
      int b = dstg[j] >> 8;
      int slot = basev[b] - hist[b] + rank[j];
      sta[slot * 2] = (unsigned)dstg[j];
      sta[slot * 2 + 1] = (unsigned)srcet[j];
    }
  __syncthreads();
  for (int i = tid; i < cnt2; i += 256) {
    unsigned dg = sta[i * 2], se = sta[i * 2 + 1];
    int b = (int)(dg >> 8);
    int dest = runstart[b] + (i - (basev[b] - hist[b]));
    staged[dest] = make_uint2(dg, se);
  }
}

__global__ void __launch_bounds__(256) k_scatter2(
    const uint2* __restrict__ staged, const int* __restrict__ bbase,
    int* __restrict__ offs, int* __restrict__ csr, int N2) {
  __shared__ int hist[256];
  __shared__ int sd[256];
  __shared__ int cur[256];
  int b = blockIdx.x, tid = threadIdx.x;
  int nb0 = b << 8;
  int nnode = min(256, N2 - nb0);
  int s0 = bbase[b], s1 = bbase[b + 1];
  hist[tid] = 0;
  __syncthreads();
  for (int i = s0 + tid; i < s1; i += 256)
    atomicAdd(&hist[(int)staged[i].x - nb0], 1);
  __syncthreads();
  int v = hist[tid];
  sd[tid] = v; __syncthreads();
  for (int off = 1; off < 256; off <<= 1) {
    int t = (tid >= off) ? sd[tid - off] : 0;
    __syncthreads();
    sd[tid] += t;
    __syncthreads();
  }
  int ex = sd[tid] - v;
  if (tid < nnode) offs[nb0 + tid] = s0 + ex;
  cur[tid] = ex;
  __syncthreads();
  for (int i = s0 + tid; i < s1; i += 256) {
    uint2 en = staged[i];
    int node = (int)en.x - nb0;
    int sl = atomicAdd(&cur[node], 1);
    csr[s0 + sl] = (int)en.y;
  }
}

// ---- 6a. xt[r][n][c] = x_n @ W_r, fused [sq|sk] = x @ [Wq|Wk] ---------------
__global__ void __launch_bounds__(256) k_gemm_xt(
    const float* __restrict__ x1, const float* __restrict__ x2,
    const u16* __restrict__ Wb, const u16* __restrict__ Bqk,
    u16* __restrict__ xt, unsigned long long xt_gstride,
    float* __restrict__ sq, float* __restrict__ sk,
    int N, int R, int g0) {
  __shared__ u16 st[4][2][2048];  // 4 waves x 2 buffers x 4KB
  int g = g0 + blockIdx.z;
  const float* x = g ? x2 : x1;
  const u16* Wbg = Wb + (size_t)g * (R * 4) * 4096;
  const u16* Bqkg = Bqk + (size_t)g * 2048;
  u16* xtg = xt + (size_t)g * xt_gstride;
  int node_base = g * N;
  int wave = threadIdx.x >> 6, lane = threadIdx.x & 63;
  int m0 = blockIdx.x * 64 + wave * 16;
  int rbase = blockIdx.y * 4;
  int q = lane >> 4, m16 = lane & 15;
  int node = m0 + m16;
  int srow = (node < N) ? node : N - 1;
  short8 bfrag[4];
#pragma unroll
  for (int kk = 0; kk < 4; ++kk) {
    const float* ap = x + (size_t)srow * 128 + kk * 32 + q * 8;
    float4v f0 = *(const float4v*)ap;
    float4v f1 = *(const float4v*)(ap + 4);
    union { unsigned u[4]; short8 s; } pb;
    pb.u[0] = cvtpk(f0.x, f0.y); pb.u[1] = cvtpk(f0.z, f0.w);
    pb.u[2] = cvtpk(f1.x, f1.y); pb.u[3] = cvtpk(f1.z, f1.w);
    bfrag[kk] = pb.s;
  }
  if (blockIdx.y == 0) {
    floatx4 accq = (floatx4){0.f, 0.f, 0.f, 0.f};
#pragma unroll
    for (int kk = 0; kk < 4; ++kk) {
      short8 aq = *(const short8*)(Bqkg + (size_t)kk * 512 + lane * 8);
      accq = __builtin_amdgcn_mfma_f32_16x16x32_bf16(aq, bfrag[kk], accq, 0, 0, 0);
    }
    if (node < N) {
      float* dst = (q < 2 ? sq : sk) + (size_t)(node_base + node) * 8 + (q & 1) * 4;
      *(float4v*)dst = (float4v){accq[0], accq[1], accq[2], accq[3]};
    }
  }
#pragma unroll
  for (int rr = 0; rr < 4; ++rr) {
    int r = rbase + rr;
    u16* s = st[wave][rr & 1];
    floatx4 acc[8];
#pragma unroll
    for (int nt = 0; nt < 8; ++nt) acc[nt] = (floatx4){0.f, 0.f, 0.f, 0.f};
#pragma unroll
    for (int kk = 0; kk < 4; ++kk) {
      const u16* wbp = Wbg + ((size_t)((r * 4 + kk) * 8) * 64 + lane) * 8;
#pragma unroll
      for (int nt = 0; nt < 8; ++nt) {
        short8 a = *(const short8*)(wbp + nt * 512);
        acc[nt] = __builtin_amdgcn_mfma_f32_16x16x32_bf16(a, bfrag[kk], acc[nt], 0, 0, 0);
      }
    }
#pragma unroll
    for (int nt = 0; nt < 8; ++nt) {
      union { unsigned u[2]; unsigned long long ull; } pk;
      pk.u[0] = cvtpk(acc[nt][0], acc[nt][1]);
      pk.u[1] = cvtpk(acc[nt][2], acc[nt][3]);
      int c16 = 2 * nt + (q >> 1);
      *(unsigned long long*)(s + (((m16 << 4) + (c16 ^ m16)) << 3) + ((q & 1) << 2)) = pk.ull;
    }
#pragma unroll
    for (int it = 0; it < 4; ++it) {
      int rl = it * 4 + q;
      int gm = m0 + rl;
      if (gm < N) {
        uint4v vv = *(const uint4v*)(s + (((rl << 4) + (m16 ^ rl)) << 3));
        *(uint4v*)(xtg + ((size_t)r * N + gm) * 128 + m16 * 8) = vv;
      }
    }
  }
}

// ---- 6b. per-dst softmax + gather: one wave per node ------------------------
__global__ void __launch_bounds__(256) k_aggregate(
    const int* __restrict__ csr, const int* __restrict__ offs,
    const float* __restrict__ sq, const float* __restrict__ sk,
    const u16* __restrict__ xt, unsigned long long xt_gstride,
    const float* __restrict__ b1, const float* __restrict__ b2,
    float* __restrict__ out, int N, int g0) {
  int nl = blockIdx.x * 4 + (threadIdx.x >> 6);
  int lane = threadIdx.x & 63;
  if (nl >= N) return;
  int g = g0 + blockIdx.y;
  int node_base = g * N;
  const float* bias = g ? b2 : b1;
  const u16* xtg = xt + (size_t)g * xt_gstride;
  float* outp = out + (size_t)g * N * 128;
  int node = node_base + nl;
  int start = offs[node], end = offs[node + 1];
  const float* sqn = sq + (size_t)node * 8;

  float al[8]; int pl[8];
  float m = -INFINITY;
  {
    int c = 0;
    for (int i = start + lane; i < end; i += 64, ++c) {
      int p = csr[i]; int s = p >> 3, e = p & 7;
      float a = sqn[e] + sk[(size_t)(node_base + s) * 8 + e];
      a = (a > 0.f) ? a : 0.2f * a;
      if (c < 8) { al[c] = a; pl[c] = p; }
      m = fmaxf(m, a);
    }
  }
#pragma unroll
  for (int off = 32; off; off >>= 1) m = fmaxf(m, __shfl_xor(m, off));

  float ssum = 0.f;
  {
    int c = 0;
    for (int i = start + lane; i < end; i += 64, ++c) {
      float a;
      if (c < 8) a = al[c];
      else {
        int p = csr[i]; int s = p >> 3, e = p & 7;
        a = sqn[e] + sk[(size_t)(node_base + s) * 8 + e];
        a = (a > 0.f) ? a : 0.2f * a;
      }
      ssum += __expf(a - m);
    }
  }
#pragma unroll
  for (int off = 32; off; off >>= 1) ssum += __shfl_xor(ssum, off);
  float inv = 1.f / (ssum + 1e-16f);

  float acc0 = 0.f, acc1 = 0.f;
  const char* xtb = (const char*)xtg;
  int c = 0;
  for (int base = start; base < end; base += 64, ++c) {
    int cnt = min(64, end - base);
    float w = 0.f; int b = 0;
    {
      int i = base + lane;
      if (i < end) {
        int p; float a;
        if (c < 8) { p = pl[c]; a = al[c]; }
        else {
          p = csr[i]; int s = p >> 3, e = p & 7;
          a = sqn[e] + sk[(size_t)(node_base + s) * 8 + e];
          a = (a > 0.f) ? a : 0.2f * a;
        }
        w = __expf(a - m) * inv;
        b = ((p & 7) * N + (p >> 3)) << 8;  // xt row base in BYTES
      }
    }
    int j = 0;
    for (; j + 3 < cnt; j += 4) {
      float w0 = __shfl(w, j), w1 = __shfl(w, j + 1),
            w2 = __shfl(w, j + 2), w3 = __shfl(w, j + 3);
      int b0 = __shfl(b, j), b1_ = __shfl(b, j + 1),
          b2_ = __shfl(b, j + 2), b3 = __shfl(b, j + 3);
      unsigned v0 = *(const unsigned*)(xtb + b0 + lane * 4);
      unsigned v1 = *(const unsigned*)(xtb + b1_ + lane * 4);
      unsigned v2 = *(const unsigned*)(xtb + b2_ + lane * 4);
      unsigned v3 = *(const unsigned*)(xtb + b3 + lane * 4);
      acc0 += w0 * bflo(v0); acc1 += w0 * bfhi(v0);
      acc0 += w1 * bflo(v1); acc1 += w1 * bfhi(v1);
      acc0 += w2 * bflo(v2); acc1 += w2 * bfhi(v2);
      acc0 += w3 * bflo(v3); acc1 += w3 * bfhi(v3);
    }
    for (; j < cnt; ++j) {
      float w0 = __shfl(w, j);
      int b0 = __shfl(b, j);
      unsigned v0 = *(const unsigned*)(xtb + b0 + lane * 4);
      acc0 += w0 * bflo(v0); acc1 += w0 * bfhi(v0);
    }
  }
  float o0 = fmaxf(acc0 + bias[lane * 2], 0.f);
  float o1 = fmaxf(acc1 + bias[lane * 2 + 1], 0.f);
  union { float f[2]; unsigned long long u; } pk;
  pk.f[0] = o0; pk.f[1] = o1;
  __builtin_nontemporal_store(pk.u,
      (unsigned long long*)(outp + (size_t)nl * 128 + lane * 2));
}

// -----------------------------------------------------------------------------
extern "C" void kernel_launch(void* const* d_in, const int* in_sizes, int n_in,
                              void* d_out, int out_size, void* d_ws, size_t ws_size,
                              hipStream_t stream) {
  const float* x1 = (const float*)d_in[0];
  const int* ei1 = (const int*)d_in[1];
  const int* et1 = (const int*)d_in[2];
  const float* x2 = (const float*)d_in[3];
  const int* ei2 = (const int*)d_in[4];
  const int* et2 = (const int*)d_in[5];
  const float* W1 = (const float*)d_in[6];
  const float* q1 = (const float*)d_in[7];
  const float* k1 = (const float*)d_in[8];
  const float* b1 = (const float*)d_in[9];
  const float* W2 = (const float*)d_in[10];
  const float* q2 = (const float*)d_in[11];
  const float* k2 = (const float*)d_in[12];
  const float* b2 = (const float*)d_in[13];

  const int N = in_sizes[0] / 128;
  const int E = in_sizes[1] / 2;
  const int R = in_sizes[6] / (128 * 128);
  const int KK = R * 4;
  const int N2 = 2 * N;
  const int NB = (N2 + 255) >> 8;           // 256-node buckets (<=512)

  size_t off = 0;
  char* w = (char*)d_ws;
  auto carve = [&](size_t bytes) -> void* {
    void* p = w + off;
    off += (bytes + 255) & ~(size_t)255;
    return p;
  };
  u16* Wb = (u16*)carve((size_t)2 * KK * 4096 * 2);
  u16* Bqk = (u16*)carve((size_t)2 * 4 * 64 * 8 * 2);
  float* sq = (float*)carve((size_t)N2 * 8 * 4);
  float* sk = (float*)carve((size_t)N2 * 8 * 4);
  int* offs = (int*)carve((size_t)(N2 + 1) * 4);
  int* gcnt = (int*)carve(512 * 4);
  int* bbase = (int*)carve(520 * 4);
  int* bcur = (int*)carve(512 * 4);
  int* csr = (int*)carve((size_t)2 * E * 4);
  // xt takes the rest; merged mode needs 2 buffers
  size_t xt_elems = (size_t)R * N * 128;
  u16* xt = (u16*)(w + off);
  bool merged = (off + 2 * xt_elems * 2) <= ws_size;
  if (off + xt_elems * 2 > ws_size) return;  // cannot run at all
  uint2* staged = (uint2*)xt;                // ALIAS: dead before gemm_xt
  unsigned long long gstride = merged ? (unsigned long long)xt_elems : 0ull;

  const int nbin = (2 * E + 4095) / 4096;
  const int nblk = nbin > NB ? nbin : NB;
  int total = 2 * E;

  hipMemsetAsync(gcnt, 0, 512 * 4, stream);
  k_prep_wb<<<dim3((KK * 512 + 255) / 256, 2), dim3(256), 0, stream>>>(W1, W2, Wb, KK);
  k_prep_bqk<<<dim3(16), dim3(256), 0, stream>>>(W1, q1, k1, W2, q2, k2, Bqk);

  // fused cooperative sort; fallback to 4-kernel path if rejected
  {
    void* args[] = {(void*)&ei1, (void*)&et1, (void*)&ei2, (void*)&et2,
                    (void*)&gcnt, (void*)&bbase, (void*)&bcur, (void*)&offs,
                    (void*)&staged, (void*)&csr,
                    (void*)&N, (void*)&E, (void*)&NB, (void*)&N2, (void*)&total};
    hipError_t err = hipLaunchCooperativeKernel(
        (void*)k_sort, dim3(nblk), dim3(256), args, 0, stream);
    if (err != hipSuccess) {
      (void)hipGetLastError();  // clear
      k_count<<<dim3(nbin), dim3(256), 0, stream>>>(ei1 + E, ei2 + E, gcnt, N, E, NB);
      k_bucket_scan<<<dim3(1), dim3(256), 0, stream>>>(gcnt, bbase, bcur, offs, NB, total, N2);
      k_bin<<<dim3(nbin), dim3(256), 0, stream>>>(ei1, et1, ei2, et2, bcur, staged, N, E, NB);
      k_scatter2<<<dim3(NB), dim3(256), 0, stream>>>(staged, bbase, offs, csr, N2);
    }
  }

  if (merged) {
    k_gemm_xt<<<dim3((N + 63) / 64, 2, 2), dim3(256), 0, stream>>>(
        x1, x2, Wb, Bqk, xt, gstride, sq, sk, N, R, 0);
    k_aggregate<<<dim3((N + 3) / 4, 2), dim3(256), 0, stream>>>(
        csr, offs, sq, sk, xt, gstride, b1, b2, (float*)d_out, N, 0);
  } else {
    for (int g = 0; g < 2; ++g) {
      k_gemm_xt<<<dim3((N + 63) / 64, 2, 1), dim3(256), 0, stream>>>(
          x1, x2, Wb, Bqk, xt, 0ull, sq, sk, N, R, g);
      k_aggregate<<<dim3((N + 3) / 4, 1), dim3(256), 0, stream>>>(
          csr, offs, sq, sk, xt, 0ull, b1, b2, (float*)d_out, N, g);
    }
  }
}

// Round 10
// 340.890 us; speedup vs baseline: 1.7804x; 1.7804x over previous
//
#include <hip/hip_runtime.h>

// RGATConv x2 (N=50000, E=800000, IN=HID=128, R=8) for MI355X/gfx950.
//
// Round-18: verified round-11 per-graph compute path (gemm dbuf+swizzle y=2,
// aggregate wave-per-node; per-graph keeps xt L3-resident — round-16 merged
// mode measured worse) + sort chain shortened by PADDED BUCKETS: each of the
// 391 buckets gets a fixed 8192-slot region (mean load 4096, sigma 64 ->
// overflow ~e^-1000), so k_bin2 self-allocates via atomicAdd(bcnt) and
// k_count/k_bucket_scan are DELETED (one edge pass instead of two, 12->9
// dispatches). k_aggregate reads ends[node] instead of offs[node+1].
// Round-17 lesson: cooperative grid.sync costs ~90us on MI355X — never on
// the critical path. cvt_pk bf16 packing kept (round-16, verified).

typedef unsigned short u16;
typedef __attribute__((ext_vector_type(8))) short short8;
typedef __attribute__((ext_vector_type(4))) float floatx4;
typedef __attribute__((ext_vector_type(4))) float float4v;
typedef __attribute__((ext_vector_type(4))) unsigned uint4v;

#define BCAP 8192  // slots per 256-node bucket (mean 4096)

__device__ __forceinline__ u16 f2bf(float f) {
  union { float f; unsigned u; } v; v.f = f;
  unsigned r = v.u + 0x7FFFu + ((v.u >> 16) & 1u);  // RNE
  return (u16)(r >> 16);
}
__device__ __forceinline__ float bflo(unsigned v) {
  union { unsigned u; float f; } c; c.u = v << 16; return c.f;
}
__device__ __forceinline__ float bfhi(unsigned v) {
  union { unsigned u; float f; } c; c.u = v & 0xffff0000u; return c.f;
}
__device__ __forceinline__ unsigned cvtpk(float lo, float hi) {
  unsigned r;
  asm("v_cvt_pk_bf16_f32 %0, %1, %2" : "=v"(r) : "v"(lo), "v"(hi));
  return r;
}

// ---- 1. pack stacked W into fragment order (per graph) ----------------------
__global__ void k_prep_wb(const float* __restrict__ W1, const float* __restrict__ W2,
                          u16* __restrict__ Wb, int KK) {
  int t = blockIdx.x * 256 + threadIdx.x;
  int lane = t & 63, nt = (t >> 6) & 7, kk = t >> 9;
  if (kk >= KK) return;
  const float* W = blockIdx.y ? W2 : W1;
  u16* out = Wb + (size_t)blockIdx.y * KK * 4096;
  int q = lane >> 4, m16 = lane & 15;
  int c = nt * 16 + m16;
  short8 v;
#pragma unroll
  for (int j = 0; j < 8; ++j) {
    int k = kk * 32 + q * 8 + j;
    v[j] = (short)f2bf(W[(size_t)k * 128 + c]);
  }
  *(short8*)(out + (size_t)t * 8) = v;
}

// ---- 2. Bqk direct: Bqk[g][kk][lane][j] = dot(W_g[r][k][:], {q|k}_g) --------
__global__ void __launch_bounds__(256) k_prep_bqk(
    const float* __restrict__ W1, const float* __restrict__ q1,
    const float* __restrict__ k1, const float* __restrict__ W2,
    const float* __restrict__ q2, const float* __restrict__ k2,
    u16* __restrict__ Bqk) {
  int idx = blockIdx.x * 256 + threadIdx.x;  // 4096 total
  int j = idx & 7, lane = (idx >> 3) & 63, kk = (idx >> 9) & 3, g = idx >> 11;
  int k = kk * 32 + ((lane >> 4) & 3) * 8 + j;
  int n = lane & 15;
  const float* W = g ? W2 : W1;
  const float* vec = (n < 8) ? (g ? q2 : q1) : (g ? k2 : k1);
  const float* row = W + ((size_t)(n & 7) * 128 + k) * 128;
  float s = 0.f;
#pragma unroll
  for (int o = 0; o < 128; o += 4) {
    float4v wv = *(const float4v*)(row + o);
    float4v qv = *(const float4v*)(vec + o);
    s += wv.x * qv.x + wv.y * qv.y + wv.z * qv.z + wv.w * qv.w;
  }
  Bqk[idx] = f2bf(s);
}

// ---- 5a. bin edges into padded 256-node buckets (one pass, self-allocating) -
__global__ void __launch_bounds__(256) k_bin2(
    const int* __restrict__ ei1, const int* __restrict__ et1,
    const int* __restrict__ ei2, const int* __restrict__ et2,
    int* __restrict__ bcnt, uint2* __restrict__ staged, int N, int E, int NB) {
  __shared__ int hist[512];
  __shared__ int basev[512];
  __shared__ int runstart[512];
  __shared__ unsigned sta[4096 * 2];  // 32 KB staging (dstg, srcet)
  int tid = threadIdx.x;
  int E2 = 2 * E;
  int e0 = blockIdx.x * 4096;
  int cnt2 = min(4096, E2 - e0);
  for (int i = tid; i < 512; i += 256) hist[i] = 0;
  __syncthreads();
  int dstg[16], srcet[16], rank[16];
#pragma unroll
  for (int j = 0; j < 16; ++j) {
    int e = e0 + j * 256 + tid;
    dstg[j] = -1;
    if (e < E2) {
      int g = e >= E;
      int el = e - (g ? E : 0);
      const int* ei = g ? ei2 : ei1;
      int s = ei[el], d = ei[E + el];
      int etv = (g ? et2 : et1)[el];
      dstg[j] = g * N + d;
      srcet[j] = (s << 3) | etv;
      rank[j] = atomicAdd(&hist[dstg[j] >> 8], 1);
    }
  }
  __syncthreads();
  basev[tid] = hist[tid];
  basev[tid + 256] = hist[tid + 256];
  __syncthreads();
  for (int off = 1; off < 512; off <<= 1) {
    int i0 = tid, i1 = tid + 256;
    int v0 = (i0 >= off) ? basev[i0 - off] : 0;
    int v1 = (i1 >= off) ? basev[i1 - off] : 0;
    __syncthreads();
    basev[i0] += v0; basev[i1] += v1;
    __syncthreads();
  }
  for (int i = tid; i < NB; i += 256)
    if (hist[i] > 0) runstart[i] = atomicAdd(&bcnt[i], hist[i]);
  __syncthreads();
#pragma unroll
  for (int j = 0; j < 16; ++j)
    if (dstg[j] >= 0) {
      int b = dstg[j] >> 8;
      int slot = basev[b] - hist[b] + rank[j];
      sta[slot * 2] = (unsigned)dstg[j];
      sta[slot * 2 + 1] = (unsigned)srcet[j];
    }
  __syncthreads();
  for (int i = tid; i < cnt2; i += 256) {
    unsigned dg = sta[i * 2], se = sta[i * 2 + 1];
    int b = (int)(dg >> 8);
    int dest = (b << 13) + runstart[b] + (i - (basev[b] - hist[b]));
    staged[dest] = make_uint2(dg, se);
  }
}

// ---- 5b. per-bucket: node-level offs/ends + sorted csr (padded space) -------
__global__ void __launch_bounds__(256) k_scatter3(
    const uint2* __restrict__ staged, const int* __restrict__ bcnt,
    int* __restrict__ offs, int* __restrict__ ends, int* __restrict__ csr,
    int N2) {
  __shared__ int hist[256];
  __shared__ int sd[256];
  __shared__ int cur[256];
  int b = blockIdx.x, tid = threadIdx.x;
  int nb0 = b << 8;
  int nnode = min(256, N2 - nb0);
  int s0 = b << 13;
  int cnt = bcnt[b];
  hist[tid] = 0;
  __syncthreads();
  for (int i = tid; i < cnt; i += 256)
    atomicAdd(&hist[(int)staged[s0 + i].x - nb0], 1);
  __syncthreads();
  int v = hist[tid];
  sd[tid] = v; __syncthreads();
  for (int off = 1; off < 256; off <<= 1) {
    int t = (tid >= off) ? sd[tid - off] : 0;
    __syncthreads();
    sd[tid] += t;
    __syncthreads();
  }
  int ex = sd[tid] - v;  // exclusive scan
  if (tid < nnode) {
    offs[nb0 + tid] = s0 + ex;
    ends[nb0 + tid] = s0 + ex + v;
  }
  cur[tid] = ex;
  __syncthreads();
  for (int i = tid; i < cnt; i += 256) {
    uint2 en = staged[s0 + i];
    int node = (int)en.x - nb0;
    int sl = atomicAdd(&cur[node], 1);
    csr[s0 + sl] = (int)en.y;
  }
}

// ---- 6a. xt[r][n][c] = x_n @ W_r, fused [sq|sk] = x @ [Wq|Wk] ---------------
// Round-11 structure (y=2: 4 relations/block, dbuf XOR-granule LDS, no
// barriers) + cvt_pk packing. Per-graph launch.
__global__ void __launch_bounds__(256) k_gemm_xt(
    const float* __restrict__ x, const u16* __restrict__ Wb,
    const u16* __restrict__ Bqk, u16* __restrict__ xt,
    float* __restrict__ sq, float* __restrict__ sk,
    int N, int R, int node_base) {
  __shared__ u16 st[4][2][2048];  // 4 waves x 2 buffers x 4KB
  int wave = threadIdx.x >> 6, lane = threadIdx.x & 63;
  int m0 = blockIdx.x * 64 + wave * 16;
  int rbase = blockIdx.y * 4;
  int q = lane >> 4, m16 = lane & 15;
  int node = m0 + m16;
  int srow = (node < N) ? node : N - 1;
  short8 bfrag[4];
#pragma unroll
  for (int kk = 0; kk < 4; ++kk) {
    const float* ap = x + (size_t)srow * 128 + kk * 32 + q * 8;
    float4v f0 = *(const float4v*)ap;
    float4v f1 = *(const float4v*)(ap + 4);
    union { unsigned u[4]; short8 s; } pb;
    pb.u[0] = cvtpk(f0.x, f0.y); pb.u[1] = cvtpk(f0.z, f0.w);
    pb.u[2] = cvtpk(f1.x, f1.y); pb.u[3] = cvtpk(f1.z, f1.w);
    bfrag[kk] = pb.s;
  }
  if (blockIdx.y == 0) {
    floatx4 accq = (floatx4){0.f, 0.f, 0.f, 0.f};
#pragma unroll
    for (int kk = 0; kk < 4; ++kk) {
      short8 aq = *(const short8*)(Bqk + (size_t)kk * 512 + lane * 8);
      accq = __builtin_amdgcn_mfma_f32_16x16x32_bf16(aq, bfrag[kk], accq, 0, 0, 0);
    }
    if (node < N) {
      float* dst = (q < 2 ? sq : sk) + (size_t)(node_base + node) * 8 + (q & 1) * 4;
      *(float4v*)dst = (float4v){accq[0], accq[1], accq[2], accq[3]};
    }
  }
#pragma unroll
  for (int rr = 0; rr < 4; ++rr) {
    int r = rbase + rr;
    u16* s = st[wave][rr & 1];
    floatx4 acc[8];
#pragma unroll
    for (int nt = 0; nt < 8; ++nt) acc[nt] = (floatx4){0.f, 0.f, 0.f, 0.f};
#pragma unroll
    for (int kk = 0; kk < 4; ++kk) {
      const u16* wbp = Wb + ((size_t)((r * 4 + kk) * 8) * 64 + lane) * 8;
#pragma unroll
      for (int nt = 0; nt < 8; ++nt) {
        short8 a = *(const short8*)(wbp + nt * 512);
        acc[nt] = __builtin_amdgcn_mfma_f32_16x16x32_bf16(a, bfrag[kk], acc[nt], 0, 0, 0);
      }
    }
    // swizzled transpose write: row m16, granule c16 = 2nt+(q>>1), half q&1
#pragma unroll
    for (int nt = 0; nt < 8; ++nt) {
      union { unsigned u[2]; unsigned long long ull; } pk;
      pk.u[0] = cvtpk(acc[nt][0], acc[nt][1]);
      pk.u[1] = cvtpk(acc[nt][2], acc[nt][3]);
      int c16 = 2 * nt + (q >> 1);
      *(unsigned long long*)(s + (((m16 << 4) + (c16 ^ m16)) << 3) + ((q & 1) << 2)) = pk.ull;
    }
    // swizzled read: row rl = it*4+q, granule m16 -> 16B chunk m16 of row rl
#pragma unroll
    for (int it = 0; it < 4; ++it) {
      int rl = it * 4 + q;
      int gm = m0 + rl;
      if (gm < N) {
        uint4v vv = *(const uint4v*)(s + (((rl << 4) + (m16 ^ rl)) << 3));
        *(uint4v*)(xt + ((size_t)r * N + gm) * 128 + m16 * 8) = vv;
      }
    }
  }
}

// ---- 6b. per-dst softmax + gather: one wave per node (ends[] variant) -------
__global__ void __launch_bounds__(256) k_aggregate(
    const int* __restrict__ csr, const int* __restrict__ offs,
    const int* __restrict__ ends,
    const float* __restrict__ sq, const float* __restrict__ sk,
    const u16* __restrict__ xt, const float* __restrict__ bias,
    float* __restrict__ out, int N, int node_base) {
  int nl = blockIdx.x * 4 + (threadIdx.x >> 6);
  int lane = threadIdx.x & 63;
  if (nl >= N) return;
  int node = node_base + nl;
  int start = offs[node], end = ends[node];
  const float* sqn = sq + (size_t)node * 8;

  float al[8]; int pl[8];
  float m = -INFINITY;
  {
    int c = 0;
    for (int i = start + lane; i < end; i += 64, ++c) {
      int p = csr[i]; int s = p >> 3, e = p & 7;
      float a = sqn[e] + sk[(size_t)(node_base + s) * 8 + e];
      a = (a > 0.f) ? a : 0.2f * a;
      if (c < 8) { al[c] = a; pl[c] = p; }
      m = fmaxf(m, a);
    }
  }
#pragma unroll
  for (int off = 32; off; off >>= 1) m = fmaxf(m, __shfl_xor(m, off));

  float ssum = 0.f;
  {
    int c = 0;
    for (int i = start + lane; i < end; i += 64, ++c) {
      float a;
      if (c < 8) a = al[c];
      else {
        int p = csr[i]; int s = p >> 3, e = p & 7;
        a = sqn[e] + sk[(size_t)(node_base + s) * 8 + e];
        a = (a > 0.f) ? a : 0.2f * a;
      }
      ssum += __expf(a - m);
    }
  }
#pragma unroll
  for (int off = 32; off; off >>= 1) ssum += __shfl_xor(ssum, off);
  float inv = 1.f / (ssum + 1e-16f);

  float acc0 = 0.f, acc1 = 0.f;
  const char* xtb = (const char*)xt;
  int c = 0;
  for (int base = start; base < end; base += 64, ++c) {
    int cnt = min(64, end - base);
    float w = 0.f; int b = 0;
    {
      int i = base + lane;
      if (i < end) {
        int p; float a;
        if (c < 8) { p = pl[c]; a = al[c]; }
        else {
          p = csr[i]; int s = p >> 3, e = p & 7;
          a = sqn[e] + sk[(size_t)(node_base + s) * 8 + e];
          a = (a > 0.f) ? a : 0.2f * a;
        }
        w = __expf(a - m) * inv;
        b = ((p & 7) * N + (p >> 3)) << 8;  // xt row base in BYTES
      }
    }
    int j = 0;
    for (; j + 3 < cnt; j += 4) {
      float w0 = __shfl(w, j), w1 = __shfl(w, j + 1),
            w2 = __shfl(w, j + 2), w3 = __shfl(w, j + 3);
      int b0 = __shfl(b, j), b1 = __shfl(b, j + 1),
          b2 = __shfl(b, j + 2), b3 = __shfl(b, j + 3);
      unsigned v0 = *(const unsigned*)(xtb + b0 + lane * 4);
      unsigned v1 = *(const unsigned*)(xtb + b1 + lane * 4);
      unsigned v2 = *(const unsigned*)(xtb + b2 + lane * 4);
      unsigned v3 = *(const unsigned*)(xtb + b3 + lane * 4);
      acc0 += w0 * bflo(v0); acc1 += w0 * bfhi(v0);
      acc0 += w1 * bflo(v1); acc1 += w1 * bfhi(v1);
      acc0 += w2 * bflo(v2); acc1 += w2 * bfhi(v2);
      acc0 += w3 * bflo(v3); acc1 += w3 * bfhi(v3);
    }
    for (; j < cnt; ++j) {
      float w0 = __shfl(w, j);
      int b0 = __shfl(b, j);
      unsigned v0 = *(const unsigned*)(xtb + b0 + lane * 4);
      acc0 += w0 * bflo(v0); acc1 += w0 * bfhi(v0);
    }
  }
  float o0 = fmaxf(acc0 + bias[lane * 2], 0.f);
  float o1 = fmaxf(acc1 + bias[lane * 2 + 1], 0.f);
  union { float f[2]; unsigned long long u; } pk;
  pk.f[0] = o0; pk.f[1] = o1;
  __builtin_nontemporal_store(pk.u,
      (unsigned long long*)(out + (size_t)nl * 128 + lane * 2));
}

// -----------------------------------------------------------------------------
extern "C" void kernel_launch(void* const* d_in, const int* in_sizes, int n_in,
                              void* d_out, int out_size, void* d_ws, size_t ws_size,
                              hipStream_t stream) {
  const float* x1 = (const float*)d_in[0];
  const int* ei1 = (const int*)d_in[1];
  const int* et1 = (const int*)d_in[2];
  const float* x2 = (const float*)d_in[3];
  const int* ei2 = (const int*)d_in[4];
  const int* et2 = (const int*)d_in[5];
  const float* W1 = (const float*)d_in[6];
  const float* q1 = (const float*)d_in[7];
  const float* k1 = (const float*)d_in[8];
  const float* b1 = (const float*)d_in[9];
  const float* W2 = (const float*)d_in[10];
  const float* q2 = (const float*)d_in[11];
  const float* k2 = (const float*)d_in[12];
  const float* b2 = (const float*)d_in[13];

  const int N = in_sizes[0] / 128;
  const int E = in_sizes[1] / 2;
  const int R = in_sizes[6] / (128 * 128);
  const int KK = R * 4;
  const int N2 = 2 * N;
  const int NB = (N2 + 255) >> 8;           // 256-node buckets (<=512)

  size_t off = 0;
  char* w = (char*)d_ws;
  auto carve = [&](size_t bytes) -> void* {
    void* p = w + off;
    off += (bytes + 255) & ~(size_t)255;
    return p;
  };
  u16* Wb = (u16*)carve((size_t)2 * KK * 4096 * 2);
  u16* Bqk = (u16*)carve((size_t)2 * 4 * 64 * 8 * 2);
  float* sq = (float*)carve((size_t)N2 * 8 * 4);
  float* sk = (float*)carve((size_t)N2 * 8 * 4);
  int* offs = (int*)carve((size_t)N2 * 4);
  int* ends = (int*)carve((size_t)N2 * 4);
  int* bcnt = (int*)carve(512 * 4);
  int* csr = (int*)carve((size_t)NB * BCAP * 4);
  u16* xt = (u16*)carve((size_t)R * N * 128 * 2);       // per-graph, reused
  uint2* staged = (uint2*)xt;                           // ALIAS: dead before gemm_xt
  if (off > ws_size) return;
  // staged needs NB*BCAP*8 bytes inside xt's region
  if ((size_t)NB * BCAP * 8 > (size_t)R * N * 128 * 2) return;

  const int nbin = (2 * E + 4095) / 4096;

  hipMemsetAsync(bcnt, 0, 512 * 4, stream);
  k_prep_wb<<<dim3((KK * 512 + 255) / 256, 2), dim3(256), 0, stream>>>(W1, W2, Wb, KK);
  k_prep_bqk<<<dim3(16), dim3(256), 0, stream>>>(W1, q1, k1, W2, q2, k2, Bqk);
  k_bin2<<<dim3(nbin), dim3(256), 0, stream>>>(ei1, et1, ei2, et2, bcnt, staged, N, E, NB);
  k_scatter3<<<dim3(NB), dim3(256), 0, stream>>>(staged, bcnt, offs, ends, csr, N2);

  for (int g = 0; g < 2; ++g) {
    const float* x = g ? x2 : x1;
    const float* bv = g ? b2 : b1;
    float* outp = (float*)d_out + (size_t)g * N * 128;
    k_gemm_xt<<<dim3((N + 63) / 64, 2), dim3(256), 0, stream>>>(
        x, Wb + (size_t)g * KK * 4096, Bqk + (size_t)g * 2048, xt,
        sq, sk, N, R, g * N);
    k_aggregate<<<dim3((N + 3) / 4), dim3(256), 0, stream>>>(
        csr, offs, ends, sq, sk, xt, bv, outp, N, g * N);
  }
}

// Round 11
// 324.198 us; speedup vs baseline: 1.8721x; 1.0515x over previous
//
#include <hip/hip_runtime.h>

// RGATConv x2 (N=50000, E=800000, IN=HID=128, R=8) for MI355X/gfx950.
//
// Round-19: dispatch-count attack. Ledger showed ~85us (25%) of round-18's
// 340.9us is launch gaps (9 dispatches x ~10us). Changes:
//  (a) k_sortgemm: bin2 (391 blocks) fused into gemm(0)'s dispatch (1564
//      blocks) — independent work, sort hides under gemm; LDS is a 38.9KB
//      union; staged gets its own carve (no xt alias).
//  (b) k_prep: prep_wb + prep_bqk + bcnt zeroing in one kernel; memset gone.
//  (c) Order prep -> [bin2||gemm0] -> scatter3 -> agg0 -> gemm1 -> agg1
//      (6 dispatches; gemm1 after agg0 keeps xt single-buffer + L3-warm).
// Compute kernels byte-identical to round-18's verified versions.

typedef unsigned short u16;
typedef __attribute__((ext_vector_type(8))) short short8;
typedef __attribute__((ext_vector_type(4))) float floatx4;
typedef __attribute__((ext_vector_type(4))) float float4v;
typedef __attribute__((ext_vector_type(4))) unsigned uint4v;

#define BCAP 8192  // slots per 256-node bucket (mean 4096, sigma 64)

__device__ __forceinline__ u16 f2bf(float f) {
  union { float f; unsigned u; } v; v.f = f;
  unsigned r = v.u + 0x7FFFu + ((v.u >> 16) & 1u);  // RNE
  return (u16)(r >> 16);
}
__device__ __forceinline__ float bflo(unsigned v) {
  union { unsigned u; float f; } c; c.u = v << 16; return c.f;
}
__device__ __forceinline__ float bfhi(unsigned v) {
  union { unsigned u; float f; } c; c.u = v & 0xffff0000u; return c.f;
}
__device__ __forceinline__ unsigned cvtpk(float lo, float hi) {
  unsigned r;
  asm("v_cvt_pk_bf16_f32 %0, %1, %2" : "=v"(r) : "v"(lo), "v"(hi));
  return r;
}

// ---- 1. merged prep: Wb fragments + Bqk direct + bcnt zero ------------------
__global__ void __launch_bounds__(256) k_prep(
    const float* __restrict__ W1, const float* __restrict__ q1,
    const float* __restrict__ k1, const float* __restrict__ W2,
    const float* __restrict__ q2, const float* __restrict__ k2,
    u16* __restrict__ Wb, u16* __restrict__ Bqk, int* __restrict__ bcnt,
    int KK, int wbHalf) {
  int b = blockIdx.x, tid = threadIdx.x;
  int wbBlocks = 2 * wbHalf;
  if (b < wbBlocks) {
    // Wb pack: Wb[g][(kk*8+nt)*512 + lane*8 + j] = W[k][c]
    int gy = b >= wbHalf;
    int t = (b - gy * wbHalf) * 256 + tid;
    int lane = t & 63, nt = (t >> 6) & 7, kk = t >> 9;
    if (kk >= KK) return;
    const float* W = gy ? W2 : W1;
    u16* out = Wb + (size_t)gy * KK * 4096;
    int q = lane >> 4, m16 = lane & 15;
    int c = nt * 16 + m16;
    short8 v;
#pragma unroll
    for (int j = 0; j < 8; ++j) {
      int k = kk * 32 + q * 8 + j;
      v[j] = (short)f2bf(W[(size_t)k * 128 + c]);
    }
    *(short8*)(out + (size_t)t * 8) = v;
  } else {
    int bb = b - wbBlocks;  // 0..15
    if (bb < 2) {
      int z = bb * 256 + tid;
      bcnt[z] = 0;
    }
    int idx = bb * 256 + tid;  // 4096 total
    int j = idx & 7, lane = (idx >> 3) & 63, kk = (idx >> 9) & 3, g = idx >> 11;
    int k = kk * 32 + ((lane >> 4) & 3) * 8 + j;
    int n = lane & 15;
    const float* W = g ? W2 : W1;
    const float* vec = (n < 8) ? (g ? q2 : q1) : (g ? k2 : k1);
    const float* row = W + ((size_t)(n & 7) * 128 + k) * 128;
    float s = 0.f;
#pragma unroll
    for (int o = 0; o < 128; o += 4) {
      float4v wv = *(const float4v*)(row + o);
      float4v qv = *(const float4v*)(vec + o);
      s += wv.x * qv.x + wv.y * qv.y + wv.z * qv.z + wv.w * qv.w;
    }
    Bqk[idx] = f2bf(s);
  }
}

// ---- shared-mem union for the fused sort+gemm kernel ------------------------
struct BinSmem {
  int hist[512];
  int basev[512];
  int runstart[512];
  unsigned sta[8192];  // 32 KB
};
union SortGemmSmem {
  BinSmem bn;
  u16 st[4][2][2048];  // gemm staging: 4 waves x 2 buffers x 4KB
};

// ---- 2. fused: blocks [0,nbin) = bin2; blocks [nbin, nbin+2*gx) = gemm(g=0) -
__global__ void __launch_bounds__(256) k_sortgemm(
    const int* __restrict__ ei1, const int* __restrict__ et1,
    const int* __restrict__ ei2, const int* __restrict__ et2,
    int* __restrict__ bcnt, uint2* __restrict__ staged,
    const float* __restrict__ x, const u16* __restrict__ Wb,
    const u16* __restrict__ Bqk, u16* __restrict__ xt,
    float* __restrict__ sq, float* __restrict__ sk,
    int N, int E, int NB, int R, int nbin, int gx) {
  __shared__ SortGemmSmem sm;
  int tid = threadIdx.x;

  if ((int)blockIdx.x < nbin) {
    // ---------------- bin2: padded-bucket counting sort ----------------
    int* hist = sm.bn.hist;
    int* basev = sm.bn.basev;
    int* runstart = sm.bn.runstart;
    unsigned* sta = sm.bn.sta;
    int E2 = 2 * E;
    int e0 = blockIdx.x * 4096;
    int cnt2 = min(4096, E2 - e0);
    for (int i = tid; i < 512; i += 256) hist[i] = 0;
    __syncthreads();
    int dstg[16], srcet[16], rank[16];
#pragma unroll
    for (int j = 0; j < 16; ++j) {
      int e = e0 + j * 256 + tid;
      dstg[j] = -1;
      if (e < E2) {
        int g = e >= E;
        int el = e - (g ? E : 0);
        const int* ei = g ? ei2 : ei1;
        int s = ei[el], d = ei[E + el];
        int etv = (g ? et2 : et1)[el];
        dstg[j] = g * N + d;
        srcet[j] = (s << 3) | etv;
        rank[j] = atomicAdd(&hist[dstg[j] >> 8], 1);
      }
    }
    __syncthreads();
    basev[tid] = hist[tid];
    basev[tid + 256] = hist[tid + 256];
    __syncthreads();
    for (int off = 1; off < 512; off <<= 1) {
      int i0 = tid, i1 = tid + 256;
      int v0 = (i0 >= off) ? basev[i0 - off] : 0;
      int v1 = (i1 >= off) ? basev[i1 - off] : 0;
      __syncthreads();
      basev[i0] += v0; basev[i1] += v1;
      __syncthreads();
    }
    for (int i = tid; i < NB; i += 256)
      if (hist[i] > 0) runstart[i] = atomicAdd(&bcnt[i], hist[i]);
    __syncthreads();
#pragma unroll
    for (int j = 0; j < 16; ++j)
      if (dstg[j] >= 0) {
        int b = dstg[j] >> 8;
        int slot = basev[b] - hist[b] + rank[j];
        sta[slot * 2] = (unsigned)dstg[j];
        sta[slot * 2 + 1] = (unsigned)srcet[j];
      }
    __syncthreads();
    for (int i = tid; i < cnt2; i += 256) {
      unsigned dg = sta[i * 2], se = sta[i * 2 + 1];
      int b = (int)(dg >> 8);
      int dest = (b << 13) + runstart[b] + (i - (basev[b] - hist[b]));
      staged[dest] = make_uint2(dg, se);
    }
    return;
  }

  // ---------------- gemm(0): xt = x @ W_r, fused [sq|sk] ----------------
  int f = blockIdx.x - nbin;
  int bx = f % gx;
  int by = f / gx;
  int wave = tid >> 6, lane = tid & 63;
  int m0 = bx * 64 + wave * 16;
  int rbase = by * 4;
  int q = lane >> 4, m16 = lane & 15;
  int node = m0 + m16;
  int srow = (node < N) ? node : N - 1;
  short8 bfrag[4];
#pragma unroll
  for (int kk = 0; kk < 4; ++kk) {
    const float* ap = x + (size_t)srow * 128 + kk * 32 + q * 8;
    float4v f0 = *(const float4v*)ap;
    float4v f1 = *(const float4v*)(ap + 4);
    union { unsigned u[4]; short8 s; } pb;
    pb.u[0] = cvtpk(f0.x, f0.y); pb.u[1] = cvtpk(f0.z, f0.w);
    pb.u[2] = cvtpk(f1.x, f1.y); pb.u[3] = cvtpk(f1.z, f1.w);
    bfrag[kk] = pb.s;
  }
  if (by == 0) {
    floatx4 accq = (floatx4){0.f, 0.f, 0.f, 0.f};
#pragma unroll
    for (int kk = 0; kk < 4; ++kk) {
      short8 aq = *(const short8*)(Bqk + (size_t)kk * 512 + lane * 8);
      accq = __builtin_amdgcn_mfma_f32_16x16x32_bf16(aq, bfrag[kk], accq, 0, 0, 0);
    }
    if (node < N) {
      float* dst = (q < 2 ? sq : sk) + (size_t)node * 8 + (q & 1) * 4;
      *(float4v*)dst = (float4v){accq[0], accq[1], accq[2], accq[3]};
    }
  }
#pragma unroll
  for (int rr = 0; rr < 4; ++rr) {
    int r = rbase + rr;
    u16* s = sm.st[wave][rr & 1];
    floatx4 acc[8];
#pragma unroll
    for (int nt = 0; nt < 8; ++nt) acc[nt] = (floatx4){0.f, 0.f, 0.f, 0.f};
#pragma unroll
    for (int kk = 0; kk < 4; ++kk) {
      const u16* wbp = Wb + ((size_t)((r * 4 + kk) * 8) * 64 + lane) * 8;
#pragma unroll
      for (int nt = 0; nt < 8; ++nt) {
        short8 a = *(const short8*)(wbp + nt * 512);
        acc[nt] = __builtin_amdgcn_mfma_f32_16x16x32_bf16(a, bfrag[kk], acc[nt], 0, 0, 0);
      }
    }
#pragma unroll
    for (int nt = 0; nt < 8; ++nt) {
      union { unsigned u[2]; unsigned long long ull; } pk;
      pk.u[0] = cvtpk(acc[nt][0], acc[nt][1]);
      pk.u[1] = cvtpk(acc[nt][2], acc[nt][3]);
      int c16 = 2 * nt + (q >> 1);
      *(unsigned long long*)(s + (((m16 << 4) + (c16 ^ m16)) << 3) + ((q & 1) << 2)) = pk.ull;
    }
#pragma unroll
    for (int it = 0; it < 4; ++it) {
      int rl = it * 4 + q;
      int gm = m0 + rl;
      if (gm < N) {
        uint4v vv = *(const uint4v*)(s + (((rl << 4) + (m16 ^ rl)) << 3));
        *(uint4v*)(xt + ((size_t)r * N + gm) * 128 + m16 * 8) = vv;
      }
    }
  }
}

// ---- 3. per-bucket: node-level offs/ends + sorted csr (padded space) --------
__global__ void __launch_bounds__(256) k_scatter3(
    const uint2* __restrict__ staged, const int* __restrict__ bcnt,
    int* __restrict__ offs, int* __restrict__ ends, int* __restrict__ csr,
    int N2) {
  __shared__ int hist[256];
  __shared__ int sd[256];
  __shared__ int cur[256];
  int b = blockIdx.x, tid = threadIdx.x;
  int nb0 = b << 8;
  int nnode = min(256, N2 - nb0);
  int s0 = b << 13;
  int cnt = bcnt[b];
  hist[tid] = 0;
  __syncthreads();
  for (int i = tid; i < cnt; i += 256)
    atomicAdd(&hist[(int)staged[s0 + i].x - nb0], 1);
  __syncthreads();
  int v = hist[tid];
  sd[tid] = v; __syncthreads();
  for (int off = 1; off < 256; off <<= 1) {
    int t = (tid >= off) ? sd[tid - off] : 0;
    __syncthreads();
    sd[tid] += t;
    __syncthreads();
  }
  int ex = sd[tid] - v;  // exclusive scan
  if (tid < nnode) {
    offs[nb0 + tid] = s0 + ex;
    ends[nb0 + tid] = s0 + ex + v;
  }
  cur[tid] = ex;
  __syncthreads();
  for (int i = tid; i < cnt; i += 256) {
    uint2 en = staged[s0 + i];
    int node = (int)en.x - nb0;
    int sl = atomicAdd(&cur[node], 1);
    csr[s0 + sl] = (int)en.y;
  }
}

// ---- 4. standalone gemm for g=1 (round-18 verified) -------------------------
__global__ void __launch_bounds__(256) k_gemm_xt(
    const float* __restrict__ x, const u16* __restrict__ Wb,
    const u16* __restrict__ Bqk, u16* __restrict__ xt,
    float* __restrict__ sq, float* __restrict__ sk,
    int N, int R, int node_base) {
  __shared__ u16 st[4][2][2048];
  int wave = threadIdx.x >> 6, lane = threadIdx.x & 63;
  int m0 = blockIdx.x * 64 + wave * 16;
  int rbase = blockIdx.y * 4;
  int q = lane >> 4, m16 = lane & 15;
  int node = m0 + m16;
  int srow = (node < N) ? node : N - 1;
  short8 bfrag[4];
#pragma unroll
  for (int kk = 0; kk < 4; ++kk) {
    const float* ap = x + (size_t)srow * 128 + kk * 32 + q * 8;
    float4v f0 = *(const float4v*)ap;
    float4v f1 = *(const float4v*)(ap + 4);
    union { unsigned u[4]; short8 s; } pb;
    pb.u[0] = cvtpk(f0.x, f0.y); pb.u[1] = cvtpk(f0.z, f0.w);
    pb.u[2] = cvtpk(f1.x, f1.y); pb.u[3] = cvtpk(f1.z, f1.w);
    bfrag[kk] = pb.s;
  }
  if (blockIdx.y == 0) {
    floatx4 accq = (floatx4){0.f, 0.f, 0.f, 0.f};
#pragma unroll
    for (int kk = 0; kk < 4; ++kk) {
      short8 aq = *(const short8*)(Bqk + (size_t)kk * 512 + lane * 8);
      accq = __builtin_amdgcn_mfma_f32_16x16x32_bf16(aq, bfrag[kk], accq, 0, 0, 0);
    }
    if (node < N) {
      float* dst = (q < 2 ? sq : sk) + (size_t)(node_base + node) * 8 + (q & 1) * 4;
      *(float4v*)dst = (float4v){accq[0], accq[1], accq[2], accq[3]};
    }
  }
#pragma unroll
  for (int rr = 0; rr < 4; ++rr) {
    int r = rbase + rr;
    u16* s = st[wave][rr & 1];
    floatx4 acc[8];
#pragma unroll
    for (int nt = 0; nt < 8; ++nt) acc[nt] = (floatx4){0.f, 0.f, 0.f, 0.f};
#pragma unroll
    for (int kk = 0; kk < 4; ++kk) {
      const u16* wbp = Wb + ((size_t)((r * 4 + kk) * 8) * 64 + lane) * 8;
#pragma unroll
      for (int nt = 0; nt < 8; ++nt) {
        short8 a = *(const short8*)(wbp + nt * 512);
        acc[nt] = __builtin_amdgcn_mfma_f32_16x16x32_bf16(a, bfrag[kk], acc[nt], 0, 0, 0);
      }
    }
#pragma unroll
    for (int nt = 0; nt < 8; ++nt) {
      union { unsigned u[2]; unsigned long long ull; } pk;
      pk.u[0] = cvtpk(acc[nt][0], acc[nt][1]);
      pk.u[1] = cvtpk(acc[nt][2], acc[nt][3]);
      int c16 = 2 * nt + (q >> 1);
      *(unsigned long long*)(s + (((m16 << 4) + (c16 ^ m16)) << 3) + ((q & 1) << 2)) = pk.ull;
    }
#pragma unroll
    for (int it = 0; it < 4; ++it) {
      int rl = it * 4 + q;
      int gm = m0 + rl;
      if (gm < N) {
        uint4v vv = *(const uint4v*)(s + (((rl << 4) + (m16 ^ rl)) << 3));
        *(uint4v*)(xt + ((size_t)r * N + gm) * 128 + m16 * 8) = vv;
      }
    }
  }
}

// ---- 5. per-dst softmax + gather: one wave per node (ends[] variant) --------
__global__ void __launch_bounds__(256) k_aggregate(
    const int* __restrict__ csr, const int* __restrict__ offs,
    const int* __restrict__ ends,
    const float* __restrict__ sq, const float* __restrict__ sk,
    const u16* __restrict__ xt, const float* __restrict__ bias,
    float* __restrict__ out, int N, int node_base) {
  int nl = blockIdx.x * 4 + (threadIdx.x >> 6);
  int lane = threadIdx.x & 63;
  if (nl >= N) return;
  int node = node_base + nl;
  int start = offs[node], end = ends[node];
  const float* sqn = sq + (size_t)node * 8;

  float al[8]; int pl[8];
  float m = -INFINITY;
  {
    int c = 0;
    for (int i = start + lane; i < end; i += 64, ++c) {
      int p = csr[i]; int s = p >> 3, e = p & 7;
      float a = sqn[e] + sk[(size_t)(node_base + s) * 8 + e];
      a = (a > 0.f) ? a : 0.2f * a;
      if (c < 8) { al[c] = a; pl[c] = p; }
      m = fmaxf(m, a);
    }
  }
#pragma unroll
  for (int off = 32; off; off >>= 1) m = fmaxf(m, __shfl_xor(m, off));

  float ssum = 0.f;
  {
    int c = 0;
    for (int i = start + lane; i < end; i += 64, ++c) {
      float a;
      if (c < 8) a = al[c];
      else {
        int p = csr[i]; int s = p >> 3, e = p & 7;
        a = sqn[e] + sk[(size_t)(node_base + s) * 8 + e];
        a = (a > 0.f) ? a : 0.2f * a;
      }
      ssum += __expf(a - m);
    }
  }
#pragma unroll
  for (int off = 32; off; off >>= 1) ssum += __shfl_xor(ssum, off);
  float inv = 1.f / (ssum + 1e-16f);

  float acc0 = 0.f, acc1 = 0.f;
  const char* xtb = (const char*)xt;
  int c = 0;
  for (int base = start; base < end; base += 64, ++c) {
    int cnt = min(64, end - base);
    float w = 0.f; int b = 0;
    {
      int i = base + lane;
      if (i < end) {
        int p; float a;
        if (c < 8) { p = pl[c]; a = al[c]; }
        else {
          p = csr[i]; int s = p >> 3, e = p & 7;
          a = sqn[e] + sk[(size_t)(node_base + s) * 8 + e];
          a = (a > 0.f) ? a : 0.2f * a;
        }
        w = __expf(a - m) * inv;
        b = ((p & 7) * N + (p >> 3)) << 8;  // xt row base in BYTES
      }
    }
    int j = 0;
    for (; j + 3 < cnt; j += 4) {
      float w0 = __shfl(w, j), w1 = __shfl(w, j + 1),
            w2 = __shfl(w, j + 2), w3 = __shfl(w, j + 3);
      int b0 = __shfl(b, j), b1 = __shfl(b, j + 1),
          b2 = __shfl(b, j + 2), b3 = __shfl(b, j + 3);
      unsigned v0 = *(const unsigned*)(xtb + b0 + lane * 4);
      unsigned v1 = *(const unsigned*)(xtb + b1 + lane * 4);
      unsigned v2 = *(const unsigned*)(xtb + b2 + lane * 4);
      unsigned v3 = *(const unsigned*)(xtb + b3 + lane * 4);
      acc0 += w0 * bflo(v0); acc1 += w0 * bfhi(v0);
      acc0 += w1 * bflo(v1); acc1 += w1 * bfhi(v1);
      acc0 += w2 * bflo(v2); acc1 += w2 * bfhi(v2);
      acc0 += w3 * bflo(v3); acc1 += w3 * bfhi(v3);
    }
    for (; j < cnt; ++j) {
      float w0 = __shfl(w, j);
      int b0 = __shfl(b, j);
      unsigned v0 = *(const unsigned*)(xtb + b0 + lane * 4);
      acc0 += w0 * bflo(v0); acc1 += w0 * bfhi(v0);
    }
  }
  float o0 = fmaxf(acc0 + bias[lane * 2], 0.f);
  float o1 = fmaxf(acc1 + bias[lane * 2 + 1], 0.f);
  union { float f[2]; unsigned long long u; } pk;
  pk.f[0] = o0; pk.f[1] = o1;
  __builtin_nontemporal_store(pk.u,
      (unsigned long long*)(out + (size_t)nl * 128 + lane * 2));
}

// -----------------------------------------------------------------------------
extern "C" void kernel_launch(void* const* d_in, const int* in_sizes, int n_in,
                              void* d_out, int out_size, void* d_ws, size_t ws_size,
                              hipStream_t stream) {
  const float* x1 = (const float*)d_in[0];
  const int* ei1 = (const int*)d_in[1];
  const int* et1 = (const int*)d_in[2];
  const float* x2 = (const float*)d_in[3];
  const int* ei2 = (const int*)d_in[4];
  const int* et2 = (const int*)d_in[5];
  const float* W1 = (const float*)d_in[6];
  const float* q1 = (const float*)d_in[7];
  const float* k1 = (const float*)d_in[8];
  const float* b1 = (const float*)d_in[9];
  const float* W2 = (const float*)d_in[10];
  const float* q2 = (const float*)d_in[11];
  const float* k2 = (const float*)d_in[12];
  const float* b2 = (const float*)d_in[13];

  const int N = in_sizes[0] / 128;
  const int E = in_sizes[1] / 2;
  const int R = in_sizes[6] / (128 * 128);
  const int KK = R * 4;
  const int N2 = 2 * N;
  const int NB = (N2 + 255) >> 8;           // 256-node buckets (<=512)

  size_t off = 0;
  char* w = (char*)d_ws;
  auto carve = [&](size_t bytes) -> void* {
    void* p = w + off;
    off += (bytes + 255) & ~(size_t)255;
    return p;
  };
  u16* Wb = (u16*)carve((size_t)2 * KK * 4096 * 2);
  u16* Bqk = (u16*)carve((size_t)2 * 4 * 64 * 8 * 2);
  float* sq = (float*)carve((size_t)N2 * 8 * 4);
  float* sk = (float*)carve((size_t)N2 * 8 * 4);
  int* offs = (int*)carve((size_t)N2 * 4);
  int* ends = (int*)carve((size_t)N2 * 4);
  int* bcnt = (int*)carve(512 * 4);
  int* csr = (int*)carve((size_t)NB * BCAP * 4);
  uint2* staged = (uint2*)carve((size_t)NB * BCAP * 8);  // own carve (no alias)
  u16* xt = (u16*)carve((size_t)R * N * 128 * 2);        // per-graph, reused
  if (off > ws_size) return;

  const int nbin = (2 * E + 4095) / 4096;
  const int gx = (N + 63) / 64;
  const int wbHalf = (KK * 512 + 255) / 256;

  k_prep<<<dim3(2 * wbHalf + 16), dim3(256), 0, stream>>>(
      W1, q1, k1, W2, q2, k2, Wb, Bqk, bcnt, KK, wbHalf);
  k_sortgemm<<<dim3(nbin + 2 * gx), dim3(256), 0, stream>>>(
      ei1, et1, ei2, et2, bcnt, staged,
      x1, Wb, Bqk, xt, sq, sk, N, E, NB, R, nbin, gx);
  k_scatter3<<<dim3(NB), dim3(256), 0, stream>>>(staged, bcnt, offs, ends, csr, N2);
  k_aggregate<<<dim3((N + 3) / 4), dim3(256), 0, stream>>>(
      csr, offs, ends, sq, sk, xt, b1, (float*)d_out, N, 0);
  k_gemm_xt<<<dim3(gx, 2), dim3(256), 0, stream>>>(
      x2, Wb + (size_t)KK * 4096, Bqk + 2048, xt, sq, sk, N, R, N);
  k_aggregate<<<dim3((N + 3) / 4), dim3(256), 0, stream>>>(
      csr, offs, ends, sq, sk, xt, b2,
      (float*)d_out + (size_t)N * 128, N, N);
}